// Round 2
// baseline (9181.241 us; speedup 1.0000x reference)
//
#include <hip/hip_runtime.h>

typedef unsigned short u16;
typedef unsigned int   u32;
typedef __attribute__((ext_vector_type(8))) short bfx8;
typedef __attribute__((ext_vector_type(4))) float f32x4;

#define NN 131072      // nodes
#define NE 1500000     // edges
#define HH 128         // hidden
#define NG 12          // col groups: [sp_root, tp_root, W_0..W_9]

__device__ __forceinline__ u16 f2b(float f) {
  u32 u = __float_as_uint(f);
  u32 r = (u + 0x7FFFu + ((u >> 16) & 1u)) >> 16;
  return (u16)r;
}
__device__ __forceinline__ float b2f(u32 lo16) {
  return __uint_as_float(lo16 << 16);
}

// ---------------- edge counts (once per call; etype/dst fixed across layers) --
__global__ __launch_bounds__(256) void k_count(const int* __restrict__ et,
                                               const int* __restrict__ dst,
                                               int* __restrict__ cnt) {
  int e = blockIdx.x * 256 + threadIdx.x;
  if (e >= NE) return;
  int r = et[e];
  if (r < 0 || r >= 10) return;
  atomicAdd(&cnt[(size_t)r * NN + dst[e]], 1);
}

__global__ __launch_bounds__(256) void k_inv(int* __restrict__ cnt) {
  int i = blockIdx.x * 256 + threadIdx.x;
  if (i >= 10 * NN) return;
  int c = cnt[i]; if (c < 1) c = 1;
  ((float*)cnt)[i] = 1.0f / (float)c;   // in-place int -> float reciprocal
}

// ---------------- build W^T (bf16): Wall[g][j][k] = W_g[k][j] ----------------
__global__ __launch_bounds__(256) void k_buildw(
    const float* __restrict__ sp_root, const float* __restrict__ tp_root,
    const float* __restrict__ sp_basis, const float* __restrict__ sp_comp,
    const float* __restrict__ tp_basis, const float* __restrict__ tp_comp,
    u16* __restrict__ W) {
  int g = blockIdx.y;
  int idx = blockIdx.x * 256 + threadIdx.x;   // 0..16383
  int j = idx >> 7, k = idx & 127;
  float v = 0.f;
  if (g == 0) v = sp_root[k * 128 + j];
  else if (g == 1) v = tp_root[k * 128 + j];
  else if (g < 9) {
    int r = g - 2;
#pragma unroll
    for (int b = 0; b < 4; ++b) v += sp_comp[r * 4 + b] * sp_basis[b * 16384 + k * 128 + j];
  } else {
    int r = g - 9;
#pragma unroll
    for (int b = 0; b < 3; ++b) v += tp_comp[r * 3 + b] * tp_basis[b * 16384 + k * 128 + j];
  }
  W[(size_t)g * 16384 + j * 128 + k] = f2b(v);
}

// ---------------- MFMA GEMM: C[g][M][128] = A[M][128] @ W_g, bf16 ------------
__global__ __launch_bounds__(256) void k_gemm(const u16* __restrict__ A,
                                              const u16* __restrict__ Bt,
                                              u16* __restrict__ C) {
  __shared__ u16 As[128][136];   // +8 pad: 2-way aliasing max (free)
  __shared__ u16 Bs[128][136];
  int t = threadIdx.x;
  const u16* Ab = A + (size_t)blockIdx.x * 128 * 128;
  const u16* Bb = Bt + (size_t)blockIdx.y * 128 * 128;
  {
    int row = t >> 4;
    int ko = (t & 15) * 8;
#pragma unroll
    for (int it = 0; it < 8; ++it) {
      int r = row + it * 16;
      *(bfx8*)&As[r][ko] = *(const bfx8*)&Ab[r * 128 + ko];
      *(bfx8*)&Bs[r][ko] = *(const bfx8*)&Bb[r * 128 + ko];
    }
  }
  __syncthreads();
  int wid = t >> 6, lane = t & 63;
  int wm = (wid & 1) * 64, wn = (wid >> 1) * 64;
  int lr = lane & 15, lk = (lane >> 4) * 8;
  f32x4 acc[4][4] = {};
#pragma unroll
  for (int kk = 0; kk < 4; ++kk) {
    int k = kk * 32 + lk;
    bfx8 a[4], b[4];
#pragma unroll
    for (int m = 0; m < 4; ++m) a[m] = *(const bfx8*)&As[wm + m * 16 + lr][k];
#pragma unroll
    for (int n = 0; n < 4; ++n) b[n] = *(const bfx8*)&Bs[wn + n * 16 + lr][k];
#pragma unroll
    for (int m = 0; m < 4; ++m)
#pragma unroll
      for (int n = 0; n < 4; ++n)
        acc[m][n] = __builtin_amdgcn_mfma_f32_16x16x32_bf16(a[m], b[n], acc[m][n], 0, 0, 0);
  }
  u16* Cb = C + (size_t)blockIdx.y * NN * HH + (size_t)blockIdx.x * 128 * 128;
  int rbase = (lane >> 4) * 4;
#pragma unroll
  for (int m = 0; m < 4; ++m)
#pragma unroll
    for (int n = 0; n < 4; ++n)
#pragma unroll
      for (int v = 0; v < 4; ++v) {
        int row = wm + m * 16 + rbase + v;
        int col = wn + n * 16 + lr;
        Cb[row * 128 + col] = f2b(acc[m][n][v]);
      }
}

// ---------------- init hs or ht from one root table + bias -------------------
__global__ __launch_bounds__(256) void k_init1(const u16* __restrict__ T,
                                               const float* __restrict__ bias,
                                               float* __restrict__ dst) {
  size_t i4 = ((size_t)blockIdx.x * 256 + threadIdx.x) * 4;
  if (i4 >= (size_t)NN * HH) return;
  int j = (int)(i4 & 127);
  uint2 a = *(const uint2*)&T[i4];
  dst[i4 + 0] = b2f(a.x & 0xFFFFu) + bias[j + 0];
  dst[i4 + 1] = b2f(a.x >> 16)     + bias[j + 1];
  dst[i4 + 2] = b2f(a.y & 0xFFFFu) + bias[j + 2];
  dst[i4 + 3] = b2f(a.y >> 16)     + bias[j + 3];
}

// ---------------- edge scatter: hs/ht[dst] += T[rel][src] / cnt --------------
__global__ __launch_bounds__(256) void k_scatter(
    const u16* __restrict__ Table, const int* __restrict__ src,
    const int* __restrict__ dst, const int* __restrict__ et,
    const float* __restrict__ inv, float* __restrict__ hs,
    float* __restrict__ ht, int g0, int rlo, int rhi) {
  u32 tid = blockIdx.x * 256 + threadIdx.x;
  u32 e = tid >> 5;
  if (e >= NE) return;
  int r = et[e];
  if (r < rlo || r >= rhi) return;
  int sub = tid & 31;
  int s = src[e], d = dst[e];
  float sc = inv[(size_t)r * NN + d];
  const u16* row = Table + ((size_t)(r + 2 - g0) * NN + s) * HH + sub * 4;
  float* o = (r < 7 ? hs : ht) + (size_t)d * HH + sub * 4;
  uint2 v = *(const uint2*)row;
  unsafeAtomicAdd(o + 0, sc * b2f(v.x & 0xFFFFu));
  unsafeAtomicAdd(o + 1, sc * b2f(v.x >> 16));
  unsafeAtomicAdd(o + 2, sc * b2f(v.y & 0xFFFFu));
  unsafeAtomicAdd(o + 3, sc * b2f(v.y >> 16));
}

// ---------------- fuse: hn = relu(LN(cat(hs,ht)@Wf + fb)); h(+)= hn ----------
__global__ __launch_bounds__(256) void k_fuse(
    const float* __restrict__ hs, const float* __restrict__ ht,
    const float* __restrict__ fw, const float* __restrict__ fb,
    const float* __restrict__ lng, const float* __restrict__ lnb,
    u16* __restrict__ hb, int first) {
  __shared__ u16 Wf[256 * 128];         // 64 KiB (bf16 weights)
  __shared__ float cat[4][4][256];      // 16 KiB
  for (int i = threadIdx.x * 4; i < 256 * 128; i += 1024) {
    f32x4 v = *(const f32x4*)&fw[i];
    uint2 pk;
    pk.x = (u32)f2b(v.x) | ((u32)f2b(v.y) << 16);
    pk.y = (u32)f2b(v.z) | ((u32)f2b(v.w) << 16);
    *(uint2*)&Wf[i] = pk;
  }
  __syncthreads();
  int wid = threadIdx.x >> 6, lane = threadIdx.x & 63;
  int o0 = 2 * lane, o1 = o0 + 1;
  float fb0 = fb[o0], fb1 = fb[o1];
  float g0v = lng[o0], g1v = lng[o1], b0v = lnb[o0], b1v = lnb[o1];
  for (int base = blockIdx.x * 16; base < NN; base += gridDim.x * 16) {
    int n0 = base + wid * 4;
#pragma unroll
    for (int nd = 0; nd < 4; ++nd) {
      size_t pp = (size_t)(n0 + nd) * HH;
      cat[wid][nd][lane]       = hs[pp + lane];
      cat[wid][nd][lane + 64]  = hs[pp + lane + 64];
      cat[wid][nd][lane + 128] = ht[pp + lane];
      cat[wid][nd][lane + 192] = ht[pp + lane + 64];
    }
    float acc[4][2] = {};
    for (int f = 0; f < 256; ++f) {
      u32 w = *(const u32*)&Wf[f * 128 + o0];
      float wx = b2f(w & 0xFFFFu), wy = b2f(w >> 16);
#pragma unroll
      for (int nd = 0; nd < 4; ++nd) {
        float c = cat[wid][nd][f];
        acc[nd][0] = fmaf(c, wx, acc[nd][0]);
        acc[nd][1] = fmaf(c, wy, acc[nd][1]);
      }
    }
#pragma unroll
    for (int nd = 0; nd < 4; ++nd) {
      int n = n0 + nd;
      float v0 = acc[nd][0] + fb0, v1 = acc[nd][1] + fb1;
      float s = v0 + v1;
#pragma unroll
      for (int dx = 1; dx < 64; dx <<= 1) s += __shfl_xor(s, dx);
      float mu = s * (1.f / 128.f);
      float d0 = v0 - mu, d1 = v1 - mu;
      float q = d0 * d0 + d1 * d1;
#pragma unroll
      for (int dx = 1; dx < 64; dx <<= 1) q += __shfl_xor(q, dx);
      float rstd = rsqrtf(q * (1.f / 128.f) + 1e-5f);
      float y0 = fmaxf(d0 * rstd * g0v + b0v, 0.f);
      float y1 = fmaxf(d1 * rstd * g1v + b1v, 0.f);
      size_t pp = (size_t)n * HH;
      if (!first) {
        u32 hv = *(const u32*)&hb[pp + o0];
        y0 += b2f(hv & 0xFFFFu);
        y1 += b2f(hv >> 16);
      }
      *(u32*)&hb[pp + o0] = (u32)f2b(y0) | ((u32)f2b(y1) << 16);
    }
  }
}

// ---------------- input projection: h = x @ w_in + b_in (bf16 out) -----------
__global__ __launch_bounds__(256) void k_input(const float* __restrict__ x,
                                               const float* __restrict__ w,
                                               const float* __restrict__ bias,
                                               u16* __restrict__ hb) {
  __shared__ float Ws[64 * 128];        // 32 KiB
  __shared__ float xr[4][4][64];        // 4 KiB
  for (int i = threadIdx.x * 4; i < 64 * 128; i += 1024)
    *(f32x4*)&Ws[i] = *(const f32x4*)&w[i];
  __syncthreads();
  int wid = threadIdx.x >> 6, lane = threadIdx.x & 63;
  int o0 = 2 * lane, o1 = o0 + 1;
  float b0 = bias[o0], b1 = bias[o1];
  for (int base = blockIdx.x * 16; base < NN; base += gridDim.x * 16) {
    int n0 = base + wid * 4;
#pragma unroll
    for (int nd = 0; nd < 4; ++nd)
      xr[wid][nd][lane] = x[(size_t)(n0 + nd) * 64 + lane];
    float acc[4][2] = {};
    for (int f = 0; f < 64; ++f) {
      float2 wv = *(const float2*)&Ws[f * 128 + o0];
#pragma unroll
      for (int nd = 0; nd < 4; ++nd) {
        float c = xr[wid][nd][f];
        acc[nd][0] = fmaf(c, wv.x, acc[nd][0]);
        acc[nd][1] = fmaf(c, wv.y, acc[nd][1]);
      }
    }
#pragma unroll
    for (int nd = 0; nd < 4; ++nd) {
      size_t pp = (size_t)(n0 + nd) * HH;
      float y0 = acc[nd][0] + b0, y1 = acc[nd][1] + b1;
      *(u32*)&hb[pp + o0] = (u32)f2b(y0) | ((u32)f2b(y1) << 16);
    }
  }
}

// ---------------- head: out = relu(h@W1+b1)@W2 + b2 --------------------------
__global__ __launch_bounds__(256) void k_head(const u16* __restrict__ hbuf,
                                              const float* __restrict__ w1,
                                              const float* __restrict__ b1,
                                              const float* __restrict__ w2,
                                              const float* __restrict__ b2,
                                              float* __restrict__ out) {
  __shared__ u16 W1s[128 * 128];        // 32 KiB bf16
  __shared__ u16 W2s[128 * 32];         // 8 KiB bf16
  __shared__ float hr[4][4][128];       // 8 KiB
  __shared__ float h1[4][4][128];       // 8 KiB
  for (int i = threadIdx.x * 4; i < 128 * 128; i += 1024) {
    f32x4 v = *(const f32x4*)&w1[i];
    uint2 pk;
    pk.x = (u32)f2b(v.x) | ((u32)f2b(v.y) << 16);
    pk.y = (u32)f2b(v.z) | ((u32)f2b(v.w) << 16);
    *(uint2*)&W1s[i] = pk;
  }
  for (int i = threadIdx.x * 4; i < 128 * 32; i += 1024) {
    f32x4 v = *(const f32x4*)&w2[i];
    uint2 pk;
    pk.x = (u32)f2b(v.x) | ((u32)f2b(v.y) << 16);
    pk.y = (u32)f2b(v.z) | ((u32)f2b(v.w) << 16);
    *(uint2*)&W2s[i] = pk;
  }
  __syncthreads();
  int wid = threadIdx.x >> 6, lane = threadIdx.x & 63;
  int o0 = 2 * lane, o1 = o0 + 1;
  float bb0 = b1[o0], bb1 = b1[o1];
  int o2 = lane & 31, half = lane >> 5;
  float b2v = b2[o2];
  for (int base = blockIdx.x * 16; base < NN; base += gridDim.x * 16) {
    int n0 = base + wid * 4;
#pragma unroll
    for (int nd = 0; nd < 4; ++nd) {
      size_t pp = (size_t)(n0 + nd) * HH;
      u32 hv = *(const u32*)&hbuf[pp + o0];
      hr[wid][nd][o0] = b2f(hv & 0xFFFFu);
      hr[wid][nd][o1] = b2f(hv >> 16);
    }
    float acc[4][2] = {};
    for (int f = 0; f < 128; ++f) {
      u32 w = *(const u32*)&W1s[f * 128 + o0];
      float wx = b2f(w & 0xFFFFu), wy = b2f(w >> 16);
#pragma unroll
      for (int nd = 0; nd < 4; ++nd) {
        float c = hr[wid][nd][f];
        acc[nd][0] = fmaf(c, wx, acc[nd][0]);
        acc[nd][1] = fmaf(c, wy, acc[nd][1]);
      }
    }
#pragma unroll
    for (int nd = 0; nd < 4; ++nd) {
      h1[wid][nd][o0] = fmaxf(acc[nd][0] + bb0, 0.f);
      h1[wid][nd][o1] = fmaxf(acc[nd][1] + bb1, 0.f);
    }
#pragma unroll
    for (int nd2 = 0; nd2 < 2; ++nd2) {
      int nd = half * 2 + nd2;
      float a = 0.f;
      for (int f = 0; f < 128; ++f)
        a = fmaf(h1[wid][nd][f], b2f(W2s[f * 32 + o2]), a);
      out[(size_t)(n0 + nd) * 32 + o2] = a + b2v;
    }
  }
}

extern "C" void kernel_launch(void* const* d_in, const int* in_sizes, int n_in,
                              void* d_out, int out_size, void* d_ws, size_t ws_size,
                              hipStream_t stream) {
  const float* x        = (const float*)d_in[0];
  const int*   ei       = (const int*)d_in[1];
  const int*   et       = (const int*)d_in[2];
  const float* w_in     = (const float*)d_in[3];
  const float* b_in     = (const float*)d_in[4];
  const float* sp_basis = (const float*)d_in[5];
  const float* sp_comp  = (const float*)d_in[6];
  const float* sp_root  = (const float*)d_in[7];
  const float* sp_bias  = (const float*)d_in[8];
  const float* tp_basis = (const float*)d_in[9];
  const float* tp_comp  = (const float*)d_in[10];
  const float* tp_root  = (const float*)d_in[11];
  const float* tp_bias  = (const float*)d_in[12];
  const float* fuse_w   = (const float*)d_in[13];
  const float* fuse_b   = (const float*)d_in[14];
  const float* ln_g     = (const float*)d_in[15];
  const float* ln_b     = (const float*)d_in[16];
  const float* hw1      = (const float*)d_in[17];
  const float* hb1      = (const float*)d_in[18];
  const float* hw2      = (const float*)d_in[19];
  const float* hb2      = (const float*)d_in[20];

  char* p = (char*)d_ws;
  size_t off = 0;
  auto carve = [&](size_t bytes) {
    void* q = p + off;
    off += (bytes + 255) & ~(size_t)255;
    return q;
  };
  float* hsb  = (float*)carve((size_t)NN * HH * 4);   // 64 MiB
  float* htb  = (float*)carve((size_t)NN * HH * 4);   // 64 MiB
  u16*   hb   = (u16*)  carve((size_t)NN * HH * 2);   // 32 MiB
  int*   cnt  = (int*)  carve((size_t)10 * NN * 4);   //  5 MiB
  u16*   Wall = (u16*)  carve((size_t)NG * 16384 * 2);
  size_t tbytes = (size_t)NN * HH * 2;                // 32 MiB per table chunk
  long long avail = (long long)ws_size - (long long)off;
  int CC = (int)(avail > 0 ? avail / (long long)tbytes : 0);
  if (CC > NG) CC = NG;
  if (CC < 1) CC = 1;   // below this nothing fits; best effort
  u16* Table = (u16*)carve((size_t)CC * tbytes);

  hipMemsetAsync(cnt, 0, (size_t)10 * NN * 4, stream);
  k_count<<<(NE + 255) / 256, 256, 0, stream>>>(et, ei + NE, cnt);
  k_inv<<<(10 * NN + 255) / 256, 256, 0, stream>>>(cnt);
  k_input<<<2048, 256, 0, stream>>>(x, w_in, b_in, hb);

  const int initGrid = (int)(((size_t)NN * HH / 4 + 255) / 256);
  for (int l = 0; l < 3; ++l) {
    k_buildw<<<dim3(64, NG), 256, 0, stream>>>(
        sp_root + (size_t)l * 16384, tp_root + (size_t)l * 16384,
        sp_basis + (size_t)l * 4 * 16384, sp_comp + (size_t)l * 28,
        tp_basis + (size_t)l * 3 * 16384, tp_comp + (size_t)l * 9, Wall);
    for (int g0 = 0; g0 < NG; g0 += CC) {
      int ng = (NG - g0 < CC) ? NG - g0 : CC;
      k_gemm<<<dim3(NN / 128, ng), 256, 0, stream>>>(hb, Wall + (size_t)g0 * 16384, Table);
      if (g0 == 0)
        k_init1<<<initGrid, 256, 0, stream>>>(Table, sp_bias + l * 128, hsb);
      if (g0 <= 1 && g0 + ng > 1)
        k_init1<<<initGrid, 256, 0, stream>>>(Table + (size_t)(1 - g0) * NN * HH,
                                              tp_bias + l * 128, htb);
      int rlo = (g0 > 2 ? g0 - 2 : 0);
      int rhi = g0 + ng - 2;
      if (rhi > rlo)
        k_scatter<<<(NE * 32) / 256, 256, 0, stream>>>(
            Table, ei, ei + NE, et, (const float*)cnt, hsb, htb, g0, rlo, rhi);
    }
    k_fuse<<<2048, 256, 0, stream>>>(hsb, htb, fuse_w + (size_t)l * 32768,
                                     fuse_b + l * 128, ln_g + l * 128,
                                     ln_b + l * 128, hb, l == 0);
  }
  k_head<<<2048, 256, 0, stream>>>(hb, hw1, hb1, hw2, hb2, (float*)d_out);
}